// Round 15
// baseline (495.000 us; speedup 1.0000x reference)
//
#include <hip/hip_runtime.h>

#define B_TOT 262144
#define HID   256
#define NHEAD 8
#define BR    64       // rows per block
#define NTHR  128      // 2 waves; wave owns 32 batch rows (two 16-row tiles)

typedef __bf16 bf16_t;
typedef __attribute__((ext_vector_type(8))) __bf16 bf16x8;
typedef __attribute__((ext_vector_type(4))) float  f32x4;

// d_ws layout (bf16): 32 sequential PHASES of 16 KB. byte = ph*16384 + c*1024 + lane*16
//   ph = 3h+0 (Q) / 3h+1 (K) / 3h+2 (V), h in 0..7 : c = ks*2 + half
//        element = W[h*32 + PI(lane&15,half)][ks*32 + (lane>>4)*8 .. +8]
//        PI(m,half) = (m>>2)*8 + half*4 + (m&3)
//        (PI => attention-mix C-frag holds CONTIGUOUS true features -> out-proj B-frag)
//   ph = 24+ks (Wo) : c = jt; element = Wo[jt*16+(lane&15)][ks*32+(lane>>4)*8 ..+8]
// Every phase = 16 KB = 8 gload_lds16/thread (128 thr) -> uniform counted vmcnt(8).

#define PHASE_SYNC(N)                                                  \
  do {                                                                 \
    asm volatile("s_waitcnt vmcnt(" #N ") lgkmcnt(0)" ::: "memory");   \
    __builtin_amdgcn_s_barrier();                                      \
  } while (0)

static __device__ __forceinline__ f32x4 mfma16(bf16x8 a, bf16x8 b, f32x4 c) {
  return __builtin_amdgcn_mfma_f32_16x16x32_bf16(a, b, c, 0, 0, 0);
}

static __device__ __forceinline__ bf16x8 cvt8(float4 a, float4 b) {
  bf16x8 r;
  r[0] = (bf16_t)a.x; r[1] = (bf16_t)a.y; r[2] = (bf16_t)a.z; r[3] = (bf16_t)a.w;
  r[4] = (bf16_t)b.x; r[5] = (bf16_t)b.y; r[6] = (bf16_t)b.z; r[7] = (bf16_t)b.w;
  return r;
}

static __device__ __forceinline__ bf16x8 pin8(bf16x8 v) {
  f32x4 t = __builtin_bit_cast(f32x4, v);
  asm volatile("" : "+v"(t));
  return __builtin_bit_cast(bf16x8, t);
}

typedef __attribute__((address_space(3))) void lds_void;
typedef __attribute__((address_space(1))) void gbl_void;
static __device__ __forceinline__ void gload_lds16(const void* g, void* l) {
  __builtin_amdgcn_global_load_lds((gbl_void*)g, (lds_void*)l, 16, 0, 0);
}

// ---- one-shot weight pack (flat 32-phase layout, unchanged) ----
__global__ __launch_bounds__(256) void pack_weights(
    const float* __restrict__ Wq, const float* __restrict__ Wk,
    const float* __restrict__ Wv, const float* __restrict__ Wo,
    bf16_t* __restrict__ ws) {
  const int t     = blockIdx.x * 256 + threadIdx.x;
  const int lane  = t & 63;
  const int chunk = t >> 6;
  const int l15 = lane & 15, lg = lane >> 4;
  const float* src;
  int row, col;
  if (chunk < 384) {
    const int ph = chunk >> 4;
    const int c  = chunk & 15;
    const int h = ph / 3, w = ph % 3;
    const int ks = c >> 1, half = c & 1;
    src = (w == 0) ? Wq : (w == 1) ? Wk : Wv;
    row = h * 32 + (l15 >> 2) * 8 + half * 4 + (l15 & 3);   // PI permutation
    col = ks * 32 + lg * 8;
  } else {
    const int c  = chunk - 384;
    const int ks = c >> 4, jt = c & 15;
    src = Wo;
    row = jt * 16 + l15;
    col = ks * 32 + lg * 8;
  }
  const float* p = src + (size_t)row * HID + col;
  *(bf16x8*)(ws + (size_t)t * 8) = cvt8(*(const float4*)p, *(const float4*)(p + 4));
}

__global__ __launch_bounds__(NTHR, 1) void fused_local_aug(
    const float* __restrict__ fine, const float* __restrict__ coarse,
    const float* __restrict__ motif, const bf16_t* __restrict__ wpk,
    const float* __restrict__ bo, float* __restrict__ out) {
  __shared__ char wbuf[49152];   // 3 x 16 KB; 2 blocks/CU co-resident (96 KB)

  const int tid  = threadIdx.x;      // 0..127
  const int lane = tid & 63;
  const int wave = tid >> 6;         // 0..1
  const int l15  = lane & 15;
  const int lg   = lane >> 4;
  // lane's batch rows: tile t -> rowt[t]
  const size_t rowb = (size_t)blockIdx.x * BR + wave * 32 + l15;

  auto stage = [&](int ph) {
    char* dst = wbuf + (ph % 3) * 16384 + tid * 16;
    const char* src = (const char*)wpk + (size_t)ph * 16384 + tid * 16;
#pragma unroll
    for (int i = 0; i < 8; ++i)
      gload_lds16(src + i * 2048, dst + i * 2048);
  };

  stage(0);
  stage(1);

  // ---- X for BOTH tiles in registers: 48 x bf16x8 = 192 VGPRs ----
  bf16x8 xm[2][8], xf[2][8], xc[2][8];
#pragma unroll
  for (int t = 0; t < 2; ++t) {
    const size_t r = rowb + t * 16;
    const float* pm = motif  + r * HID + lg * 8;
    const float* pf = fine   + r * HID + lg * 8;
    const float* pc = coarse + r * HID + lg * 8;
#pragma unroll
    for (int s = 0; s < 8; ++s) {
      xm[t][s] = pin8(cvt8(*(const float4*)(pm + s * 32), *(const float4*)(pm + s * 32 + 4)));
      xf[t][s] = pin8(cvt8(*(const float4*)(pf + s * 32), *(const float4*)(pf + s * 32 + 4)));
      xc[t][s] = pin8(cvt8(*(const float4*)(pc + s * 32), *(const float4*)(pc + s * 32 + 4)));
    }
  }
  __syncthreads();   // full drain once: phases 0,1 staged for all waves

  bf16x8 mfrag[NHEAD][2];
  const f32x4 z4 = {0.f, 0.f, 0.f, 0.f};

  // SINGLE accumulator set [frag][tile]; softmax tail deferred via scalar
  // partial sums ps1/ps2 (computed at V-end, shfl/exp finished in next Q phase;
  // aV survives until that finish, then is overwritten by the next V phase).
  f32x4 aQ[2][2], aK1[2][2], aK2[2][2], aV1[2][2], aV2[2][2];
  float ps1[2], ps2[2];

#pragma unroll
  for (int h = 0; h < NHEAD; ++h) {
    {  // -- phase Q (p = 3h): Q MFMAs + deferred finish of head h-1 --
      const int p = 3 * h;
      if (p > 0) PHASE_SYNC(8);
      stage(p + 2);
#pragma unroll
      for (int t = 0; t < 2; ++t) { aQ[0][t] = z4; aQ[1][t] = z4; }
      const char* pb = wbuf + (p % 3) * 16384 + lane * 16;
      __builtin_amdgcn_s_setprio(1);
#pragma unroll
      for (int ks = 0; ks < 8; ++ks) {
        bf16x8 q0 = *(const bf16x8*)(pb + ks * 2048);
        bf16x8 q1 = *(const bf16x8*)(pb + ks * 2048 + 1024);
#pragma unroll
        for (int t = 0; t < 2; ++t) {
          aQ[0][t] = mfma16(q0, xm[t][ks], aQ[0][t]);
          aQ[1][t] = mfma16(q1, xm[t][ks], aQ[1][t]);
        }
      }
      __builtin_amdgcn_s_setprio(0);
      if (h > 0) {   // finish softmax + mix for head h-1 (overlaps Q MFMAs)
#pragma unroll
        for (int t = 0; t < 2; ++t) {
          float s1 = ps1[t], s2 = ps2[t];
          s1 += __shfl_xor(s1, 16); s1 += __shfl_xor(s1, 32);
          s2 += __shfl_xor(s2, 16); s2 += __shfl_xor(s2, 32);
          s1 *= (1.0f / 32.0f);  s2 *= (1.0f / 32.0f);   // reference: divide by d_k
          const float mx = fmaxf(s1, s2);
          const float e1 = __expf(s1 - mx), e2 = __expf(s2 - mx);
          const float a1 = e1 / (e1 + e2);
          const float a2 = 1.0f - a1;
          bf16x8 m;
#pragma unroll
          for (int r = 0; r < 4; ++r) {
            m[r]     = (bf16_t)(a1 * aV1[0][t][r] + a2 * aV2[0][t][r]);
            m[r + 4] = (bf16_t)(a1 * aV1[1][t][r] + a2 * aV2[1][t][r]);
          }
          mfrag[h - 1][t] = m;
        }
      }
    }
    {  // -- phase K (p = 3h+1) --
      const int p = 3 * h + 1;
      PHASE_SYNC(8);
      stage(p + 2);
#pragma unroll
      for (int t = 0; t < 2; ++t) {
        aK1[0][t] = z4; aK1[1][t] = z4; aK2[0][t] = z4; aK2[1][t] = z4;
      }
      const char* pb = wbuf + (p % 3) * 16384 + lane * 16;
      __builtin_amdgcn_s_setprio(1);
#pragma unroll
      for (int ks = 0; ks < 8; ++ks) {
        bf16x8 k0 = *(const bf16x8*)(pb + ks * 2048);
        bf16x8 k1 = *(const bf16x8*)(pb + ks * 2048 + 1024);
#pragma unroll
        for (int t = 0; t < 2; ++t) {
          aK1[0][t] = mfma16(k0, xf[t][ks], aK1[0][t]);
          aK1[1][t] = mfma16(k1, xf[t][ks], aK1[1][t]);
          aK2[0][t] = mfma16(k0, xc[t][ks], aK2[0][t]);
          aK2[1][t] = mfma16(k1, xc[t][ks], aK2[1][t]);
        }
      }
      __builtin_amdgcn_s_setprio(0);
    }
    {  // -- phase V (p = 3h+2): V MFMAs, then cheap scalar partial sums --
      const int p = 3 * h + 2;
      PHASE_SYNC(8);
      stage(p + 2);
#pragma unroll
      for (int t = 0; t < 2; ++t) {
        aV1[0][t] = z4; aV1[1][t] = z4; aV2[0][t] = z4; aV2[1][t] = z4;
      }
      const char* pb = wbuf + (p % 3) * 16384 + lane * 16;
      __builtin_amdgcn_s_setprio(1);
#pragma unroll
      for (int ks = 0; ks < 8; ++ks) {
        bf16x8 v0 = *(const bf16x8*)(pb + ks * 2048);
        bf16x8 v1 = *(const bf16x8*)(pb + ks * 2048 + 1024);
#pragma unroll
        for (int t = 0; t < 2; ++t) {
          aV1[0][t] = mfma16(v0, xf[t][ks], aV1[0][t]);
          aV1[1][t] = mfma16(v1, xf[t][ks], aV1[1][t]);
          aV2[0][t] = mfma16(v0, xc[t][ks], aV2[0][t]);
          aV2[1][t] = mfma16(v1, xc[t][ks], aV2[1][t]);
        }
      }
      __builtin_amdgcn_s_setprio(0);
#pragma unroll
      for (int t = 0; t < 2; ++t) {     // in-lane partials only (24 VALU ops)
        float s1 = 0.f, s2 = 0.f;
#pragma unroll
        for (int r = 0; r < 4; ++r) {
          s1 += aQ[0][t][r] * aK1[0][t][r] + aQ[1][t][r] * aK1[1][t][r];
          s2 += aQ[0][t][r] * aK2[0][t][r] + aQ[1][t][r] * aK2[1][t][r];
        }
        ps1[t] = s1; ps2[t] = s2;
      }
    }
  }
  {  // finish last head (h = 7)
#pragma unroll
    for (int t = 0; t < 2; ++t) {
      float s1 = ps1[t], s2 = ps2[t];
      s1 += __shfl_xor(s1, 16); s1 += __shfl_xor(s1, 32);
      s2 += __shfl_xor(s2, 16); s2 += __shfl_xor(s2, 32);
      s1 *= (1.0f / 32.0f);  s2 *= (1.0f / 32.0f);
      const float mx = fmaxf(s1, s2);
      const float e1 = __expf(s1 - mx), e2 = __expf(s2 - mx);
      const float a1 = e1 / (e1 + e2);
      const float a2 = 1.0f - a1;
      bf16x8 m;
#pragma unroll
      for (int r = 0; r < 4; ++r) {
        m[r]     = (bf16_t)(a1 * aV1[0][t][r] + a2 * aV2[0][t][r]);
        m[r + 4] = (bf16_t)(a1 * aV1[1][t][r] + a2 * aV2[1][t][r]);
      }
      mfrag[NHEAD - 1][t] = m;
    }
  }

  // ---- output projection: 8 pipelined Wo phases (p = 24+wp), 2 tiles ----
  f32x4 acc[16][2];
#pragma unroll
  for (int jt = 0; jt < 16; ++jt) { acc[jt][0] = z4; acc[jt][1] = z4; }

#pragma unroll
  for (int wp = 0; wp < 8; ++wp) {
    const int p = 24 + wp;
    if (wp == 7) { PHASE_SYNC(0); } else { PHASE_SYNC(8); }
    if (wp < 6) stage(p + 2);
    const char* pb = wbuf + (p % 3) * 16384 + lane * 16;
    __builtin_amdgcn_s_setprio(1);
#pragma unroll
    for (int jt = 0; jt < 16; ++jt) {
      bf16x8 wf = *(const bf16x8*)(pb + jt * 1024);
      acc[jt][0] = mfma16(wf, mfrag[wp][0], acc[jt][0]);
      acc[jt][1] = mfma16(wf, mfrag[wp][1], acc[jt][1]);
    }
    __builtin_amdgcn_s_setprio(0);
  }

  // epilogue: bias + NT stores; lane writes 16B chunks of its two rows
#pragma unroll
  for (int jt = 0; jt < 16; ++jt) {
    const int jj = jt * 16 + lg * 4;
    const float4 b4 = *(const float4*)(bo + jj);
#pragma unroll
    for (int t = 0; t < 2; ++t) {
      f32x4 o;
      o[0] = acc[jt][t][0] + b4.x;
      o[1] = acc[jt][t][1] + b4.y;
      o[2] = acc[jt][t][2] + b4.z;
      o[3] = acc[jt][t][3] + b4.w;
      __builtin_nontemporal_store(o, (f32x4*)(out + (rowb + t * 16) * HID + jj));
    }
  }
}

extern "C" void kernel_launch(void* const* d_in, const int* in_sizes, int n_in,
                              void* d_out, int out_size, void* d_ws, size_t ws_size,
                              hipStream_t stream) {
  (void)in_sizes; (void)n_in; (void)ws_size; (void)out_size;
  const float* fine   = (const float*)d_in[0];
  const float* coarse = (const float*)d_in[1];
  const float* motif  = (const float*)d_in[2];
  const float* Wq     = (const float*)d_in[3];
  const float* Wk     = (const float*)d_in[4];
  const float* Wv     = (const float*)d_in[5];
  const float* Wo     = (const float*)d_in[6];
  const float* bo     = (const float*)d_in[7];
  float* out          = (float*)d_out;
  bf16_t* wpk         = (bf16_t*)d_ws;

  pack_weights<<<128, 256, 0, stream>>>(Wq, Wk, Wv, Wo, wpk);
  fused_local_aug<<<B_TOT / BR, NTHR, 0, stream>>>(fine, coarse, motif, wpk, bo, out);
}

// Round 16
// 347.560 us; speedup vs baseline: 1.4242x; 1.4242x over previous
//
#include <hip/hip_runtime.h>

#define B_TOT 262144
#define HID   256
#define NHEAD 8
#define BR    64       // rows per block
#define NTHR  256      // 4 waves; wave owns 16 batch rows end-to-end

typedef __bf16 bf16_t;
typedef __attribute__((ext_vector_type(8))) __bf16 bf16x8;
typedef __attribute__((ext_vector_type(4))) float  f32x4;

// d_ws layout (bf16): 32 sequential PHASES of 16 KB. byte = ph*16384 + c*1024 + lane*16
//   ph = 3h+0 (Q) / 3h+1 (K) / 3h+2 (V), h in 0..7 : c = ks*2 + half
//        element = W[h*32 + PI(lane&15,half)][ks*32 + (lane>>4)*8 .. +8]
//        PI(m,half) = (m>>2)*8 + half*4 + (m&3)
//        (PI => attention-mix C-frag holds CONTIGUOUS true features -> out-proj B-frag)
//   ph = 24+ks (Wo) : c = jt; element = Wo[jt*16+(lane&15)][ks*32+(lane>>4)*8 ..+8]
// 4 LDS buffers of 16 KB; phase p reads buffer p%4; stage(p+2) issued inside
// phase p (writes buffer read in phase p-2, closed by the pair barrier).
// Barrier only at EVEN phases: at pair start the only outstanding vmem are the
// two stages issued a full pair (~2 phases) earlier -> vmcnt(0) is ~free.
// lgkmcnt(0) (per-wave ds_read drain) + barrier-arrival closes the WAR window
// for mid-pair stage issues (R9/R10 analysis).
#define PAIR_SYNC()                                                    \
  do {                                                                 \
    asm volatile("s_waitcnt vmcnt(0) lgkmcnt(0)" ::: "memory");        \
    __builtin_amdgcn_s_barrier();                                      \
  } while (0)

static __device__ __forceinline__ f32x4 mfma16(bf16x8 a, bf16x8 b, f32x4 c) {
  return __builtin_amdgcn_mfma_f32_16x16x32_bf16(a, b, c, 0, 0, 0);
}

static __device__ __forceinline__ bf16x8 cvt8(float4 a, float4 b) {
  bf16x8 r;
  r[0] = (bf16_t)a.x; r[1] = (bf16_t)a.y; r[2] = (bf16_t)a.z; r[3] = (bf16_t)a.w;
  r[4] = (bf16_t)b.x; r[5] = (bf16_t)b.y; r[6] = (bf16_t)b.z; r[7] = (bf16_t)b.w;
  return r;
}

static __device__ __forceinline__ bf16x8 pin8(bf16x8 v) {
  f32x4 t = __builtin_bit_cast(f32x4, v);
  asm volatile("" : "+v"(t));
  return __builtin_bit_cast(bf16x8, t);
}

typedef __attribute__((address_space(3))) void lds_void;
typedef __attribute__((address_space(1))) void gbl_void;
static __device__ __forceinline__ void gload_lds16(const void* g, void* l) {
  __builtin_amdgcn_global_load_lds((gbl_void*)g, (lds_void*)l, 16, 0, 0);
}

// ---- one-shot weight pack (flat 32-phase layout, unchanged) ----
__global__ __launch_bounds__(256) void pack_weights(
    const float* __restrict__ Wq, const float* __restrict__ Wk,
    const float* __restrict__ Wv, const float* __restrict__ Wo,
    bf16_t* __restrict__ ws) {
  const int t     = blockIdx.x * 256 + threadIdx.x;
  const int lane  = t & 63;
  const int chunk = t >> 6;
  const int l15 = lane & 15, lg = lane >> 4;
  const float* src;
  int row, col;
  if (chunk < 384) {
    const int ph = chunk >> 4;
    const int c  = chunk & 15;
    const int h = ph / 3, w = ph % 3;
    const int ks = c >> 1, half = c & 1;
    src = (w == 0) ? Wq : (w == 1) ? Wk : Wv;
    row = h * 32 + (l15 >> 2) * 8 + half * 4 + (l15 & 3);   // PI permutation
    col = ks * 32 + lg * 8;
  } else {
    const int c  = chunk - 384;
    const int ks = c >> 4, jt = c & 15;
    src = Wo;
    row = jt * 16 + l15;
    col = ks * 32 + lg * 8;
  }
  const float* p = src + (size_t)row * HID + col;
  *(bf16x8*)(ws + (size_t)t * 8) = cvt8(*(const float4*)p, *(const float4*)(p + 4));
}

__global__ __launch_bounds__(NTHR, 2) void fused_local_aug(
    const float* __restrict__ fine, const float* __restrict__ coarse,
    const float* __restrict__ motif, const bf16_t* __restrict__ wpk,
    const float* __restrict__ bo, float* __restrict__ out) {
  __shared__ char wbuf[65536];   // 4 x 16 KB; 2 blocks/CU (128 KB)

  const int tid  = threadIdx.x;
  const int lane = tid & 63;
  const int wave = tid >> 6;
  const int l15  = lane & 15;
  const int lg   = lane >> 4;
  const size_t mrow = (size_t)blockIdx.x * BR + wave * 16 + l15;

  auto stage = [&](int ph) {
    if (ph >= 32) return;
    char* dst = wbuf + (ph & 3) * 16384 + tid * 16;
    const char* src = (const char*)wpk + (size_t)ph * 16384 + tid * 16;
#pragma unroll
    for (int i = 0; i < 4; ++i)
      gload_lds16(src + i * 4096, dst + i * 4096);
  };

  stage(0);
  stage(1);

  bf16x8 xm[8], xf[8], xc[8];
  {
    const float* pm = motif  + mrow * HID + lg * 8;
    const float* pf = fine   + mrow * HID + lg * 8;
    const float* pc = coarse + mrow * HID + lg * 8;
#pragma unroll
    for (int s = 0; s < 8; ++s) {
      xm[s] = pin8(cvt8(*(const float4*)(pm + s * 32), *(const float4*)(pm + s * 32 + 4)));
      xf[s] = pin8(cvt8(*(const float4*)(pf + s * 32), *(const float4*)(pf + s * 32 + 4)));
      xc[s] = pin8(cvt8(*(const float4*)(pc + s * 32), *(const float4*)(pc + s * 32 + 4)));
    }
  }
  __syncthreads();   // pair-sync for phases {0,1}: full drain, all staged

  bf16x8 mfrag[NHEAD];
  const f32x4 z4 = {0.f, 0.f, 0.f, 0.f};

  // double accumulator sets: softmax of head h-1 runs inside head h's Q phase
  f32x4 aQ0[2], aQ1[2], aK10[2], aK11[2], aK20[2], aK21[2],
        aV10[2], aV11[2], aV20[2], aV21[2];

#pragma unroll
  for (int h = 0; h < NHEAD; ++h) {
    const int cur = h & 1, prv = cur ^ 1;   // compile-time after unroll
    {  // -- phase Q (p = 3h) --
      const int p = 3 * h;
      if (p > 0 && (p & 1) == 0) PAIR_SYNC();
      stage(p + 2);
      aQ0[cur] = z4; aQ1[cur] = z4;
      const char* pb = wbuf + (p & 3) * 16384 + lane * 16;
      __builtin_amdgcn_s_setprio(1);
#pragma unroll
      for (int ks = 0; ks < 8; ++ks) {
        bf16x8 q0 = *(const bf16x8*)(pb + ks * 2048);
        bf16x8 q1 = *(const bf16x8*)(pb + ks * 2048 + 1024);
        aQ0[cur] = mfma16(q0, xm[ks], aQ0[cur]);
        aQ1[cur] = mfma16(q1, xm[ks], aQ1[cur]);
      }
      __builtin_amdgcn_s_setprio(0);
      if (h > 0) {   // deferred softmax + mix for head h-1 (overlaps Q MFMAs)
        float s1 = 0.f, s2 = 0.f;
#pragma unroll
        for (int r = 0; r < 4; ++r) {
          s1 += aQ0[prv][r] * aK10[prv][r] + aQ1[prv][r] * aK11[prv][r];
          s2 += aQ0[prv][r] * aK20[prv][r] + aQ1[prv][r] * aK21[prv][r];
        }
        s1 += __shfl_xor(s1, 16); s1 += __shfl_xor(s1, 32);
        s2 += __shfl_xor(s2, 16); s2 += __shfl_xor(s2, 32);
        s1 *= (1.0f / 32.0f);  s2 *= (1.0f / 32.0f);   // reference divides by d_k
        const float mx = fmaxf(s1, s2);
        const float e1 = __expf(s1 - mx), e2 = __expf(s2 - mx);
        const float a1 = e1 / (e1 + e2);
        const float a2 = 1.0f - a1;
        bf16x8 t;
#pragma unroll
        for (int r = 0; r < 4; ++r) {
          t[r]     = (bf16_t)(a1 * aV10[prv][r] + a2 * aV20[prv][r]);
          t[r + 4] = (bf16_t)(a1 * aV11[prv][r] + a2 * aV21[prv][r]);
        }
        mfrag[h - 1] = t;
      }
    }
    {  // -- phase K (p = 3h+1) --
      const int p = 3 * h + 1;
      if ((p & 1) == 0) PAIR_SYNC();
      stage(p + 2);
      aK10[cur] = z4; aK11[cur] = z4; aK20[cur] = z4; aK21[cur] = z4;
      const char* pb = wbuf + (p & 3) * 16384 + lane * 16;
      __builtin_amdgcn_s_setprio(1);
#pragma unroll
      for (int ks = 0; ks < 8; ++ks) {
        bf16x8 k0 = *(const bf16x8*)(pb + ks * 2048);
        bf16x8 k1 = *(const bf16x8*)(pb + ks * 2048 + 1024);
        aK10[cur] = mfma16(k0, xf[ks], aK10[cur]);
        aK11[cur] = mfma16(k1, xf[ks], aK11[cur]);
        aK20[cur] = mfma16(k0, xc[ks], aK20[cur]);
        aK21[cur] = mfma16(k1, xc[ks], aK21[cur]);
      }
      __builtin_amdgcn_s_setprio(0);
    }
    {  // -- phase V (p = 3h+2) --
      const int p = 3 * h + 2;
      if ((p & 1) == 0) PAIR_SYNC();
      stage(p + 2);
      aV10[cur] = z4; aV11[cur] = z4; aV20[cur] = z4; aV21[cur] = z4;
      const char* pb = wbuf + (p & 3) * 16384 + lane * 16;
      __builtin_amdgcn_s_setprio(1);
#pragma unroll
      for (int ks = 0; ks < 8; ++ks) {
        bf16x8 v0 = *(const bf16x8*)(pb + ks * 2048);
        bf16x8 v1 = *(const bf16x8*)(pb + ks * 2048 + 1024);
        aV10[cur] = mfma16(v0, xf[ks], aV10[cur]);
        aV11[cur] = mfma16(v1, xf[ks], aV11[cur]);
        aV20[cur] = mfma16(v0, xc[ks], aV20[cur]);
        aV21[cur] = mfma16(v1, xc[ks], aV21[cur]);
      }
      __builtin_amdgcn_s_setprio(0);
    }
  }
  {  // softmax + mix for the last head (h = 7, set index 1)
    const int prv = 1;
    float s1 = 0.f, s2 = 0.f;
#pragma unroll
    for (int r = 0; r < 4; ++r) {
      s1 += aQ0[prv][r] * aK10[prv][r] + aQ1[prv][r] * aK11[prv][r];
      s2 += aQ0[prv][r] * aK20[prv][r] + aQ1[prv][r] * aK21[prv][r];
    }
    s1 += __shfl_xor(s1, 16); s1 += __shfl_xor(s1, 32);
    s2 += __shfl_xor(s2, 16); s2 += __shfl_xor(s2, 32);
    s1 *= (1.0f / 32.0f);  s2 *= (1.0f / 32.0f);
    const float mx = fmaxf(s1, s2);
    const float e1 = __expf(s1 - mx), e2 = __expf(s2 - mx);
    const float a1 = e1 / (e1 + e2);
    const float a2 = 1.0f - a1;
    bf16x8 t;
#pragma unroll
    for (int r = 0; r < 4; ++r) {
      t[r]     = (bf16_t)(a1 * aV10[prv][r] + a2 * aV20[prv][r]);
      t[r + 4] = (bf16_t)(a1 * aV11[prv][r] + a2 * aV21[prv][r]);
    }
    mfrag[NHEAD - 1] = t;
  }

  // ---- output projection: 8 Wo phases (p = 24+wp), pair-synced ----
  f32x4 acc[16];
#pragma unroll
  for (int jt = 0; jt < 16; ++jt) acc[jt] = z4;

#pragma unroll
  for (int wp = 0; wp < 8; ++wp) {
    const int p = 24 + wp;
    if ((p & 1) == 0) PAIR_SYNC();
    stage(p + 2);                      // no-ops past phase 31
    bf16x8 m = mfrag[wp];
    const char* pb = wbuf + (p & 3) * 16384 + lane * 16;
    __builtin_amdgcn_s_setprio(1);
#pragma unroll
    for (int jt = 0; jt < 16; ++jt) {
      bf16x8 wf = *(const bf16x8*)(pb + jt * 1024);
      acc[jt] = mfma16(wf, m, acc[jt]);
    }
    __builtin_amdgcn_s_setprio(0);
  }

  // epilogue: bias + NT stores; lane writes 16B chunks of its own full row
#pragma unroll
  for (int jt = 0; jt < 16; ++jt) {
    const int jj = jt * 16 + lg * 4;
    const float4 b4 = *(const float4*)(bo + jj);
    f32x4 o;
    o[0] = acc[jt][0] + b4.x;
    o[1] = acc[jt][1] + b4.y;
    o[2] = acc[jt][2] + b4.z;
    o[3] = acc[jt][3] + b4.w;
    __builtin_nontemporal_store(o, (f32x4*)(out + mrow * HID + jj));
  }
}

extern "C" void kernel_launch(void* const* d_in, const int* in_sizes, int n_in,
                              void* d_out, int out_size, void* d_ws, size_t ws_size,
                              hipStream_t stream) {
  (void)in_sizes; (void)n_in; (void)ws_size; (void)out_size;
  const float* fine   = (const float*)d_in[0];
  const float* coarse = (const float*)d_in[1];
  const float* motif  = (const float*)d_in[2];
  const float* Wq     = (const float*)d_in[3];
  const float* Wk     = (const float*)d_in[4];
  const float* Wv     = (const float*)d_in[5];
  const float* Wo     = (const float*)d_in[6];
  const float* bo     = (const float*)d_in[7];
  float* out          = (float*)d_out;
  bf16_t* wpk         = (bf16_t*)d_ws;

  pack_weights<<<128, 256, 0, stream>>>(Wq, Wk, Wv, Wo, wpk);
  fused_local_aug<<<B_TOT / BR, NTHR, 0, stream>>>(fine, coarse, motif, wpk, bo, out);
}